// Round 5
// baseline (1044.053 us; speedup 1.0000x reference)
//
#include <hip/hip_runtime.h>
#include <stdint.h>

// ----------------------------------------------------------------------------
// HebbianLayer on MI355X (gfx950).
// B=8, T=4096, D=768, d_inner=1536, reference CHUNK=64.
// R3: scan re-chunked to C=1024 -> parallel GEMMs.  R4: streaming conv.
// R5: (a) double-buffered LDS staging with s_waitcnt vmcnt(8) in all
//     GEMM-family K-loops (prev: full vmcnt(0) drain exposed ~900cyc HBM
//     latency every 64-K iter -> MfmaUtil 19%); (b) wstate recurrence
//     factored into parallel ugemm (1152 blocks) + in-place wcombine;
//     (c) pmat launches only lower-tri tiles.
// ----------------------------------------------------------------------------

typedef short bf16s;                                            // raw bf16 bits
typedef __attribute__((ext_vector_type(8))) short short8;       // 4 VGPR mfma frag
typedef __attribute__((ext_vector_type(4))) float f32x4;        // mfma acc

#define DEVINL __device__ __forceinline__

DEVINL float bf2f(short s) {
    union { unsigned u; float f; } v; v.u = ((unsigned)(unsigned short)s) << 16; return v.f;
}
DEVINL short f2bf(float f) {
    union { float f; unsigned u; } v; v.f = f;
    unsigned r = v.u + 0x7fffu + ((v.u >> 16) & 1u);            // RNE
    return (short)(r >> 16);
}

// async global->LDS, 16B per lane. LDS dest must be wave-uniform.
DEVINL void glds16(void* lds, const void* g) {
    __builtin_amdgcn_global_load_lds(
        (const __attribute__((address_space(1))) void*)g,
        (__attribute__((address_space(3))) void*)lds, 16, 0, 0);
}
DEVINL void wait_vm8() { asm volatile("s_waitcnt vmcnt(8)" ::: "memory"); }
DEVINL void wait_vm0() { asm volatile("s_waitcnt vmcnt(0)" ::: "memory"); }

// Stage a 128-row x 64-col bf16 tile (4 glds16 per wave = 8/wave per A+B pair).
// g must be pre-offset by sr*gstride + sf*8 (sr=tid>>3, sf=(tid&7)^(sr&7)).
DEVINL void stage128(bf16s* lds, const bf16s* g, long gstride, int wave) {
#pragma unroll
    for (int p = 0; p < 4; ++p)
        glds16(lds + p * 2048 + wave * 512, g + (long)p * 32 * gstride);
}

// Read an A/B fragment from a swizzled 64-col tile.
DEVINL short8 fragr(const bf16s* t, int row, int kk, int q) {
    int f = kk * 4 + q;
    return *(const short8*)(t + row * 64 + ((f ^ (row & 7)) * 8));
}

#define MFMA(a, b, c) __builtin_amdgcn_mfma_f32_16x16x32_bf16((a), (b), (c), 0, 0, 0)

// 128x128 tile compute step (one 64-K slab), 4 waves in 2x2.
DEVINL void comp44(const bf16s* cA, const bf16s* cB, f32x4 (&acc)[4][4],
                   int wm, int wn, int ln15, int q) {
#pragma unroll
    for (int kk = 0; kk < 2; ++kk) {
        short8 af[4], bf_[4];
#pragma unroll
        for (int i = 0; i < 4; ++i) af[i] = fragr(cA, wm * 64 + i * 16 + ln15, kk, q);
#pragma unroll
        for (int j = 0; j < 4; ++j) bf_[j] = fragr(cB, wn * 64 + j * 16 + ln15, kk, q);
#pragma unroll
        for (int i = 0; i < 4; ++i)
#pragma unroll
            for (int j = 0; j < 4; ++j) acc[i][j] = MFMA(af[i], bf_[j], acc[i][j]);
    }
}

// ---------------------------------------------------------------------------
// K0: weight casts (fp32 -> bf16). w_pg = [proj_w ; gate_w] rows (3072x768).
// ---------------------------------------------------------------------------
__global__ __launch_bounds__(256) void cast_w_kernel(
    const float* __restrict__ proj, const float* __restrict__ gate,
    const float* __restrict__ op, const float* __restrict__ wr, const float* __restrict__ rd,
    bf16s* __restrict__ w_pg, bf16s* __restrict__ w_op, bf16s* __restrict__ w_wr,
    bf16s* __restrict__ w_rd) {
    long i = (long)blockIdx.x * 256 + threadIdx.x;
    if (i < 1179648)        w_pg[i] = f2bf(proj[i]);
    else if (i < 2359296)   w_pg[i] = f2bf(gate[i - 1179648]);
    else if (i < 3538944)   w_op[i - 2359296] = f2bf(op[i - 2359296]);
    else if (i < 4128768)   w_wr[i - 3538944] = f2bf(wr[i - 3538944]);
    else if (i < 4718592)   w_rd[i - 4128768] = f2bf(rd[i - 4128768]);
}

// ---------------------------------------------------------------------------
// K1: RMSNorm + cast. One block per row (768 elems).
// ---------------------------------------------------------------------------
__global__ __launch_bounds__(256) void rmsnorm_kernel(
    const float* __restrict__ x, const float* __restrict__ w, bf16s* __restrict__ xn) {
    long row = blockIdx.x;
    const float* xr = x + row * 768;
    int tid = threadIdx.x;
    float v0 = xr[tid], v1 = xr[tid + 256], v2 = xr[tid + 512];
    float ss = v0 * v0 + v1 * v1 + v2 * v2;
#pragma unroll
    for (int off = 32; off; off >>= 1) ss += __shfl_down(ss, off);
    __shared__ float p[4];
    if ((tid & 63) == 0) p[tid >> 6] = ss;
    __syncthreads();
    float tot = p[0] + p[1] + p[2] + p[3];
    float s = rsqrtf(tot * (1.0f / 768.0f) + 1e-5f);
    bf16s* o = xn + row * 768;
    o[tid]       = f2bf(v0 * s * w[tid]);
    o[tid + 256] = f2bf(v1 * s * w[tid + 256]);
    o[tid + 512] = f2bf(v2 * s * w[tid + 512]);
}

// ---------------------------------------------------------------------------
// GEMM: C[M,N] = A[M,K] @ B[N,K]^T. 128x128 tile, BK=64, dbuf staging.
// MODE 0: store bf16.   MODE 1: d_out = x + bf2f(outres) + exp(la)*acc (f32).
// ---------------------------------------------------------------------------
template <int MODE>
__global__ __launch_bounds__(256, 2) void gemm_kernel(
    const bf16s* __restrict__ A, const bf16s* __restrict__ B, int K, int N,
    bf16s* __restrict__ Cb, const float* __restrict__ xres,
    const bf16s* __restrict__ outres, const float* __restrict__ p_la,
    float* __restrict__ Cout) {
    __shared__ bf16s sA[2][8192];
    __shared__ bf16s sB[2][8192];
    const int tid = threadIdx.x;
    const int wave = tid >> 6, lane = tid & 63;
    const int wm = wave >> 1, wn = wave & 1;
    const int ln15 = lane & 15, q = lane >> 4;
    const long m0 = (long)blockIdx.y * 128, n0 = (long)blockIdx.x * 128;
    const int sr = tid >> 3;
    const int sf = (tid & 7) ^ (sr & 7);
    const bf16s* gA = A + (m0 + sr) * K + sf * 8;
    const bf16s* gB = B + (n0 + sr) * K + sf * 8;
    float alpha = 0.f;
    if (MODE == 1) alpha = __expf(p_la[0]);
    wait_vm0();                                  // clean vmcnt bookkeeping
    f32x4 acc[4][4] = {};
    const int nkt = K >> 6;
    stage128(sA[0], gA, K, wave);
    stage128(sB[0], gB, K, wave);
    gA += 64; gB += 64;
    for (int kt = 0; kt < nkt; ++kt) {
        const bf16s* cA = sA[kt & 1];
        const bf16s* cB = sB[kt & 1];
        if (kt + 1 < nkt) {
            stage128(sA[(kt + 1) & 1], gA, K, wave);
            stage128(sB[(kt + 1) & 1], gB, K, wave);
            gA += 64; gB += 64;
            wait_vm8();
        } else wait_vm0();
        __syncthreads();
        comp44(cA, cB, acc, wm, wn, ln15, q);
        __syncthreads();
    }
#pragma unroll
    for (int i = 0; i < 4; ++i)
#pragma unroll
        for (int j = 0; j < 4; ++j) {
            long mb = m0 + wm * 64 + i * 16 + q * 4;
            long nc = n0 + wn * 64 + j * 16 + ln15;
#pragma unroll
            for (int e = 0; e < 4; ++e) {
                long m = mb + e;
                float v = acc[i][j][e];
                if (MODE == 0) {
                    Cb[m * N + nc] = f2bf(v);
                } else {
                    long idx = m * 768 + nc;
                    Cout[idx] = xres[idx] + bf2f(outres[idx]) + alpha * v;
                }
            }
        }
}

// ---------------------------------------------------------------------------
// K3: depthwise causal conv(4) + bias + SiLU, gated by SiLU(gate).
// Sliding-window streaming: thread owns 8 channels x 16 time steps.
// ---------------------------------------------------------------------------
__global__ __launch_bounds__(192) void conv_kernel(
    const bf16s* __restrict__ pg, const float* __restrict__ cw,
    const float* __restrict__ cb, bf16s* __restrict__ vg) {
    const int e0 = threadIdx.x * 8;
    const long l0 = (long)blockIdx.x * 16;
    float w0[8], w1[8], w2[8], w3[8], bias[8];
#pragma unroll
    for (int i = 0; i < 8; ++i) {
        const float* wc = cw + (e0 + i) * 4;
        w0[i] = wc[0]; w1[i] = wc[1]; w2[i] = wc[2]; w3[i] = wc[3];
        bias[i] = cb[e0 + i];
    }
    const bf16s* base = pg + l0 * 3072 + e0;
    short8 h0, h1, h2;
    if ((l0 & 4095) == 0) {
        short8 z = {0, 0, 0, 0, 0, 0, 0, 0};
        h0 = z; h1 = z; h2 = z;
    } else {
        h0 = *(const short8*)(base - 3 * 3072);
        h1 = *(const short8*)(base - 2 * 3072);
        h2 = *(const short8*)(base - 1 * 3072);
    }
    short8 cur = *(const short8*)base;
    short8 g8  = *(const short8*)(base + 1536);
    bf16s* out = vg + l0 * 1536 + e0;
#pragma unroll 4
    for (int t = 0; t < 16; ++t) {
        short8 ncur, ng;
        if (t < 15) {
            ncur = *(const short8*)(base + 3072);
            ng   = *(const short8*)(base + 3072 + 1536);
        }
        short8 o;
#pragma unroll
        for (int i = 0; i < 8; ++i) {
            float vv = bias[i] + bf2f(h0[i]) * w0[i] + bf2f(h1[i]) * w1[i]
                     + bf2f(h2[i]) * w2[i] + bf2f(cur[i]) * w3[i];
            float sv = vv / (1.0f + __expf(-vv));
            float gg = bf2f(g8[i]);
            o[i] = f2bf(sv * (gg / (1.0f + __expf(-gg))));
        }
        *(short8*)out = o;
        h0 = h1; h1 = h2; h2 = cur;
        cur = ncur; g8 = ng;
        base += 3072; out += 1536;
    }
}

// ---------------------------------------------------------------------------
// K5: transpose [b][t][e] -> [b][e][t], optional shift (t -> t-1, zero fill)
// and optional gw scale gamma^(1023 - t%1024). bf16 -> bf16.
// ---------------------------------------------------------------------------
template <int SHIFT, int GW>
__global__ __launch_bounds__(256) void transpose_kernel(
    const bf16s* __restrict__ src, bf16s* __restrict__ dst,
    const float* __restrict__ p_decay) {
    int b = blockIdx.z;
    long t0 = (long)blockIdx.y * 64, e0 = (long)blockIdx.x * 64;
    __shared__ bf16s tile[64][72];
    int tid = threadIdx.x;
    int r = tid >> 2, cs = (tid & 3) * 16;
    long tsrc = t0 + r - SHIFT;
    if (tsrc >= 0) {
        const bf16s* s = src + ((long)b * 4096 + tsrc) * 768 + e0 + cs;
        short8 v0 = *(const short8*)s;
        short8 v1 = *(const short8*)(s + 8);
        if (GW) {
            float gm = 1.0f / (1.0f + __expf(-p_decay[0]));
            float gwf = exp2f(__log2f(gm) * (float)(1023 - (int)(tsrc & 1023)));
#pragma unroll
            for (int i = 0; i < 8; ++i) {
                tile[r][cs + i]     = f2bf(bf2f(v0[i]) * gwf);
                tile[r][cs + 8 + i] = f2bf(bf2f(v1[i]) * gwf);
            }
        } else {
#pragma unroll
            for (int i = 0; i < 8; ++i) {
                tile[r][cs + i]     = v0[i];
                tile[r][cs + 8 + i] = v1[i];
            }
        }
    } else {
#pragma unroll
        for (int i = 0; i < 16; ++i) tile[r][cs + i] = 0;
    }
    __syncthreads();
    int er = tid >> 2, ts = (tid & 3) * 16;
    short8 a, bb;
#pragma unroll
    for (int i = 0; i < 8; ++i) a[i] = tile[ts + i][er];
#pragma unroll
    for (int i = 0; i < 8; ++i) bb[i] = tile[ts + 8 + i][er];
    bf16s* d = dst + ((long)b * 768 + e0 + er) * 4096 + t0 + ts;
    *(short8*)d = a;
    *(short8*)(d + 8) = bb;
}

// ---------------------------------------------------------------------------
// K6a: U[b,jc][vd,kd] = sum_{t in chunk jc} v'[t,vd]*k[t,kd], stored bf16
// into the Wst slot for jc. Fully parallel: grid (36, 4, 8).
// ---------------------------------------------------------------------------
__global__ __launch_bounds__(256, 2) void ugemm_kernel(
    const bf16s* __restrict__ vTs, const bf16s* __restrict__ oTs,
    bf16s* __restrict__ Wst) {
    __shared__ bf16s sA[2][8192];
    __shared__ bf16s sB[2][8192];
    const int b = blockIdx.z, jc = blockIdx.y;
    const int ti = blockIdx.x % 6, tj = blockIdx.x / 6;
    const int tid = threadIdx.x;
    const int wave = tid >> 6, lane = tid & 63;
    const int wm = wave >> 1, wn = wave & 1;
    const int ln15 = lane & 15, q = lane >> 4;
    const int sr = tid >> 3;
    const int sf = (tid & 7) ^ (sr & 7);
    const bf16s* gA = vTs + ((long)b * 768 + ti * 128 + sr) * 4096 + jc * 1024 + sf * 8;
    const bf16s* gB = oTs + ((long)b * 768 + tj * 128 + sr) * 4096 + jc * 1024 + sf * 8;
    f32x4 acc[4][4] = {};
    stage128(sA[0], gA, 4096, wave);
    stage128(sB[0], gB, 4096, wave);
    gA += 64; gB += 64;
    for (int kt = 0; kt < 16; ++kt) {
        const bf16s* cA = sA[kt & 1];
        const bf16s* cB = sB[kt & 1];
        if (kt + 1 < 16) {
            stage128(sA[(kt + 1) & 1], gA, 4096, wave);
            stage128(sB[(kt + 1) & 1], gB, 4096, wave);
            gA += 64; gB += 64;
            wait_vm8();
        } else wait_vm0();
        __syncthreads();
        comp44(cA, cB, acc, wm, wn, ln15, q);
        __syncthreads();
    }
    bf16s* Wj = Wst + (long)(b * 4 + jc) * 589824;
#pragma unroll
    for (int i = 0; i < 4; ++i)
#pragma unroll
        for (int jj = 0; jj < 4; ++jj) {
            long mb = ti * 128 + wm * 64 + i * 16 + q * 4;
            long nc = tj * 128 + wn * 64 + jj * 16 + ln15;
#pragma unroll
            for (int e = 0; e < 4; ++e)
                Wj[(mb + e) * 768 + nc] = f2bf(acc[i][jj][e]);
        }
}

// ---------------------------------------------------------------------------
// K6b: in-place prefix combine over the 4 U slots (descending j, thread-
// private elements): Wst[3]=gC^2 U0+gC U1+U2; [2]=gC U0+U1; [1]=U0; [0]=0.
// ---------------------------------------------------------------------------
__global__ __launch_bounds__(256) void wcombine_kernel(
    bf16s* __restrict__ Wst, const float* __restrict__ p_decay) {
    const int b = blockIdx.y;
    const long o = ((long)blockIdx.x * 256 + threadIdx.x) * 8;
    const float gm = 1.0f / (1.0f + __expf(-p_decay[0]));
    const float gC = exp2f(__log2f(gm) * 1024.0f);
    bf16s* s0 = Wst + (long)(b * 4 + 0) * 589824 + o;
    bf16s* s1 = Wst + (long)(b * 4 + 1) * 589824 + o;
    bf16s* s2 = Wst + (long)(b * 4 + 2) * 589824 + o;
    bf16s* s3 = Wst + (long)(b * 4 + 3) * 589824 + o;
    short8 u0 = *(short8*)s0, u1 = *(short8*)s1, u2 = *(short8*)s2;
    short8 w2, w3, z = {0, 0, 0, 0, 0, 0, 0, 0};
#pragma unroll
    for (int i = 0; i < 8; ++i) {
        float f0 = bf2f(u0[i]), f1 = bf2f(u1[i]), f2 = bf2f(u2[i]);
        w2[i] = f2bf(gC * f0 + f1);
        w3[i] = f2bf(gC * (gC * f0 + f1) + f2);
    }
    *(short8*)s3 = w3;
    *(short8*)s2 = w2;
    *(short8*)s1 = u0;
    *(short8*)s0 = z;
}

// ---------------------------------------------------------------------------
// K7: P'[b,j][c][c'] = bf16( (r_c . k_c') * gamma^(c-1024) * (c>c') ).
// Grid launches only lower-tri tiles: blockIdx.x in [0,36) -> (ci,cj).
// ---------------------------------------------------------------------------
__global__ __launch_bounds__(256, 2) void pmat_kernel(
    const bf16s* __restrict__ outb, bf16s* __restrict__ P,
    const float* __restrict__ p_decay) {
    int rem = blockIdx.x, ci = 0;
    while (rem >= ci + 1) { rem -= ci + 1; ci++; }
    const int cj = rem;
    const int j = blockIdx.y, b = blockIdx.z;
    const bool fix = (j == 0 && cj == 0);
    __shared__ bf16s sA[2][8192];
    __shared__ bf16s sB[2][8192];
    const int tid = threadIdx.x;
    const int wave = tid >> 6, lane = tid & 63;
    const int wm = wave >> 1, wn = wave & 1;
    const int ln15 = lane & 15, q = lane >> 4;
    const int sr = tid >> 3;
    const int sf = (tid & 7) ^ (sr & 7);
    const float lg = __log2f(1.0f / (1.0f + __expf(-p_decay[0])));
    wait_vm0();
    const bf16s* gA = outb + ((long)b * 4096 + j * 1024 + ci * 128 + sr) * 768 + sf * 8;
    const bf16s* gB = outb + ((long)b * 4096 + j * 1024 + cj * 128 + sr - 1) * 768 + sf * 8;
    f32x4 acc[4][4] = {};
    stage128(sA[0], gA, 768, wave);
    stage128(sB[0], gB, 768, wave);
    gA += 64; gB += 64;
    for (int kt = 0; kt < 12; ++kt) {
        const bf16s* cA = sA[kt & 1];
        bf16s* cB = sB[kt & 1];
        if (kt + 1 < 12) {
            stage128(sA[(kt + 1) & 1], gA, 768, wave);
            stage128(sB[(kt + 1) & 1], gB, 768, wave);
            gA += 64; gB += 64;
            wait_vm8();
        } else wait_vm0();
        __syncthreads();
        if (fix) {                         // B row 0 is global t=-1 -> zero
            if (tid < 8) { short8 zz = {0,0,0,0,0,0,0,0}; ((short8*)cB)[tid] = zz; }
            __syncthreads();
        }
        comp44(cA, cB, acc, wm, wn, ln15, q);
        __syncthreads();
    }
    bf16s* Pb = P + ((long)(b * 4 + j) << 20);
#pragma unroll
    for (int i = 0; i < 4; ++i)
#pragma unroll
        for (int jj = 0; jj < 4; ++jj) {
            int cb_ = ci * 128 + wm * 64 + i * 16 + q * 4;
            int cp  = cj * 128 + wn * 64 + jj * 16 + ln15;
#pragma unroll
            for (int e = 0; e < 4; ++e) {
                int c = cb_ + e;
                float val = (c > cp) ? acc[i][jj][e] * exp2f(lg * (float)(c - 1024)) : 0.0f;
                Pb[(long)c * 1024 + cp] = f2bf(val);
            }
        }
}

// ---------------------------------------------------------------------------
// K8: reads[c, vd] = gamma^(c%1024) * (r_c @ Wst[b,j]^T)   [skip for j==0]
//                  + P'[b,j] @ vTs^T                        (K limited to c'<=c)
// Two K-phases, dbuf-chained across the phase boundary.
// ---------------------------------------------------------------------------
__global__ __launch_bounds__(256, 2) void reads_kernel(
    const bf16s* __restrict__ outb, const bf16s* __restrict__ Wst,
    const bf16s* __restrict__ Pm, const bf16s* __restrict__ vTs,
    bf16s* __restrict__ readsb, const float* __restrict__ p_decay) {
    const int ci = blockIdx.x & 7, vi = blockIdx.x >> 3;
    const int j = blockIdx.y, b = blockIdx.z;
    __shared__ bf16s sA[2][8192];
    __shared__ bf16s sB[2][8192];
    const int tid = threadIdx.x;
    const int wave = tid >> 6, lane = tid & 63;
    const int wm = wave >> 1, wn = wave & 1;
    const int ln15 = lane & 15, q = lane >> 4;
    const int sr = tid >> 3;
    const int sf = (tid & 7) ^ (sr & 7);
    const float lg = __log2f(1.0f / (1.0f + __expf(-p_decay[0])));
    wait_vm0();
    const bf16s* gA2 = Pm + ((long)(b * 4 + j) << 20) + (long)(ci * 128 + sr) * 1024 + sf * 8;
    const bf16s* gB2 = vTs + ((long)b * 768 + vi * 128 + sr) * 4096 + j * 1024 + sf * 8;
    f32x4 acc[4][4] = {};
    if (j > 0) {
        const bf16s* gA = outb + ((long)b * 4096 + j * 1024 + ci * 128 + sr) * 768 + sf * 8;
        const bf16s* gB = Wst + ((long)(b * 4 + j) * 768 + vi * 128 + sr) * 768 + sf * 8;
        stage128(sA[0], gA, 768, wave);
        stage128(sB[0], gB, 768, wave);
        gA += 64; gB += 64;
        for (int kt = 0; kt < 12; ++kt) {
            const bf16s* cA = sA[kt & 1];
            const bf16s* cB = sB[kt & 1];
            if (kt + 1 < 12) {
                stage128(sA[(kt + 1) & 1], gA, 768, wave);
                stage128(sB[(kt + 1) & 1], gB, 768, wave);
                gA += 64; gB += 64;
            } else {               // chain: stage intra tile 0 (parity (12)&1=0)
                stage128(sA[0], gA2, 1024, wave);
                stage128(sB[0], gB2, 4096, wave);
                gA2 += 64; gB2 += 64;
            }
            wait_vm8();
            __syncthreads();
            comp44(cA, cB, acc, wm, wn, ln15, q);
            __syncthreads();
        }
        // scale inter part by gamma^(c mod 1024) while intra tile 0 flies
#pragma unroll
        for (int i = 0; i < 4; ++i) {
            int cb_ = ci * 128 + wm * 64 + i * 16 + q * 4;
#pragma unroll
            for (int e = 0; e < 4; ++e) {
                float s = exp2f(lg * (float)(cb_ + e));
#pragma unroll
                for (int jj = 0; jj < 4; ++jj) acc[i][jj][e] *= s;
            }
        }
    } else {
        stage128(sA[0], gA2, 1024, wave);
        stage128(sB[0], gB2, 4096, wave);
        gA2 += 64; gB2 += 64;
    }
    const int nkt2 = 2 * (ci + 1);
    for (int kt = 0; kt < nkt2; ++kt) {
        const bf16s* cA = sA[kt & 1];
        const bf16s* cB = sB[kt & 1];
        if (kt + 1 < nkt2) {
            stage128(sA[(kt + 1) & 1], gA2, 1024, wave);
            stage128(sB[(kt + 1) & 1], gB2, 4096, wave);
            gA2 += 64; gB2 += 64;
            wait_vm8();
        } else wait_vm0();
        __syncthreads();
        comp44(cA, cB, acc, wm, wn, ln15, q);
        __syncthreads();
    }
#pragma unroll
    for (int i = 0; i < 4; ++i)
#pragma unroll
        for (int jj = 0; jj < 4; ++jj) {
            long tb = (long)j * 1024 + ci * 128 + wm * 64 + i * 16 + q * 4;
            long nc = vi * 128 + wn * 64 + jj * 16 + ln15;
#pragma unroll
            for (int e = 0; e < 4; ++e)
                readsb[((long)b * 4096 + tb + e) * 768 + nc] = f2bf(acc[i][jj][e]);
        }
}

// ---------------------------------------------------------------------------
extern "C" void kernel_launch(void* const* d_in, const int* in_sizes, int n_in,
                              void* d_out, int out_size, void* d_ws, size_t ws_size,
                              hipStream_t stream) {
    (void)in_sizes; (void)n_in; (void)out_size;
    const float* x      = (const float*)d_in[0];
    const float* norm_w = (const float*)d_in[1];
    const float* proj_w = (const float*)d_in[2];
    const float* gate_w = (const float*)d_in[3];
    const float* conv_w = (const float*)d_in[4];
    const float* conv_b = (const float*)d_in[5];
    const float* op_w   = (const float*)d_in[6];
    const float* wr_w   = (const float*)d_in[7];
    const float* rd_w   = (const float*)d_in[8];
    const float* decay  = (const float*)d_in[9];
    const float* la     = (const float*)d_in[10];

    // -------- workspace layout (liveness overlays), ~312.4 MB total --------
    char* ws = (char*)d_ws;
    size_t off = 0;
    auto alloc = [&](size_t bytes) { void* p = ws + off; off += (bytes + 255) & ~(size_t)255; return p; };
    bf16s* w_pg = (bf16s*)alloc(3072l * 768 * 2);          // 4.7 MB
    bf16s* w_op = (bf16s*)alloc(768l * 1536 * 2);          // 2.4 MB
    bf16s* w_wr = (bf16s*)alloc(768l * 768 * 2);           // 1.2 MB
    bf16s* w_rd = (bf16s*)alloc(768l * 768 * 2);           // 1.2 MB
    bf16s* RA   = (bf16s*)alloc(32768l * 768 * 2);         // 50.3 MB: xn | vTs
    bf16s* RB   = (bf16s*)alloc(2 * 32768l * 768 * 2);     // 100.7 MB: pg | vb+oTs | P'
    bf16s* RC   = (bf16s*)alloc(2 * 32768l * 768 * 2);     // 100.7 MB: vg | Wst+reads
    bf16s* RE   = (bf16s*)alloc(32768l * 768 * 2);         // 50.3 MB: outb
    if (ws_size < off) return;   // diagnostic guard: fail clean, don't fault

    bf16s* xn    = RA;
    bf16s* vTs   = RA;
    bf16s* pgH   = RB;                     // 16384 x 3072 (one M-half)
    bf16s* vb    = RB;                     // [0:50.3 MB]
    bf16s* oTs   = RB + 25165824;          // [50.3:100.7 MB]
    bf16s* Pm    = RB;                     // 67.1 MB (after vb & oTs are dead)
    bf16s* vg    = RC;                     // 32768 x 1536
    bf16s* Wst   = RC;                     // 37.75 MB (after vg dead)
    bf16s* readsb= RC + 18874368;          // [37.75:88.1 MB]
    bf16s* outb  = RE;

    hipLaunchKernelGGL(cast_w_kernel, dim3(18432), dim3(256), 0, stream,
                       proj_w, gate_w, op_w, wr_w, rd_w, w_pg, w_op, w_wr, w_rd);
    hipLaunchKernelGGL(rmsnorm_kernel, dim3(32768), dim3(256), 0, stream, x, norm_w, xn);
    // proj+gate GEMM + conv, split at the batch-4 boundary (no conv halo)
    for (int h = 0; h < 2; ++h) {
        hipLaunchKernelGGL(HIP_KERNEL_NAME(gemm_kernel<0>), dim3(24, 128), dim3(256), 0, stream,
                           xn + (long)h * 16384 * 768, w_pg, 768, 3072, pgH,
                           (const float*)nullptr, (const bf16s*)nullptr, la, (float*)nullptr);
        hipLaunchKernelGGL(conv_kernel, dim3(1024), dim3(192), 0, stream,
                           pgH, conv_w, conv_b, vg + (long)h * 16384 * 1536);
    }
    hipLaunchKernelGGL(HIP_KERNEL_NAME(gemm_kernel<0>), dim3(6, 256), dim3(256), 0, stream,
                       vg, w_op, 1536, 768, outb,
                       (const float*)nullptr, (const bf16s*)nullptr, la, (float*)nullptr);
    hipLaunchKernelGGL(HIP_KERNEL_NAME(gemm_kernel<0>), dim3(6, 256), dim3(256), 0, stream,
                       outb, w_wr, 768, 768, vb,
                       (const float*)nullptr, (const bf16s*)nullptr, la, (float*)nullptr);
    hipLaunchKernelGGL(HIP_KERNEL_NAME(transpose_kernel<1, 0>), dim3(12, 64, 8), dim3(256), 0, stream,
                       outb, oTs, decay);
    hipLaunchKernelGGL(HIP_KERNEL_NAME(transpose_kernel<0, 1>), dim3(12, 64, 8), dim3(256), 0, stream,
                       vb, vTs, decay);
    hipLaunchKernelGGL(ugemm_kernel, dim3(36, 4, 8), dim3(256), 0, stream,
                       vTs, oTs, Wst);
    hipLaunchKernelGGL(wcombine_kernel, dim3(288, 8), dim3(256), 0, stream,
                       Wst, decay);
    hipLaunchKernelGGL(pmat_kernel, dim3(36, 4, 8), dim3(256), 0, stream,
                       outb, Pm, decay);          // clobbers vb+oTs (both dead)
    hipLaunchKernelGGL(reads_kernel, dim3(48, 4, 8), dim3(256), 0, stream,
                       outb, Wst, Pm, vTs, readsb, decay);
    hipLaunchKernelGGL(HIP_KERNEL_NAME(gemm_kernel<1>), dim3(6, 256), dim3(256), 0, stream,
                       readsb, w_rd, 768, 768, (bf16s*)nullptr,
                       x, outb, la, (float*)d_out);
}